// Round 1
// baseline (521.359 us; speedup 1.0000x reference)
//
#include <hip/hip_runtime.h>
#include <hip/hip_bf16.h>

typedef unsigned short ushort;
typedef __attribute__((ext_vector_type(8))) __bf16 bf16x8;
typedef __attribute__((ext_vector_type(4))) float f32x4;
typedef __attribute__((ext_vector_type(8))) ushort ushort8;

__device__ inline ushort f2bf(float f) {
    union { float f; unsigned u; } a{f};
    unsigned r = a.u + 0x7FFFu + ((a.u >> 16) & 1u);
    return (ushort)(r >> 16);
}
__device__ inline float gelu_f(float x) {
    return 0.5f * x * (1.f + erff(x * 0.70710678118654752f));
}

// ---------------- transpose weight [K,N] fp32 -> [N,K] bf16 ----------------
__global__ void transpose_to_bf16(const float* __restrict__ Wm, ushort* __restrict__ Wt, int K, int N) {
    __shared__ float tile[32][33];
    int k0 = blockIdx.x * 32, n0 = blockIdx.y * 32;
    int tx = threadIdx.x, ty = threadIdx.y;
    #pragma unroll
    for (int r = ty; r < 32; r += 8) tile[r][tx] = Wm[(size_t)(k0 + r) * N + n0 + tx];
    __syncthreads();
    #pragma unroll
    for (int r = ty; r < 32; r += 8) Wt[(size_t)(n0 + r) * K + k0 + tx] = f2bf(tile[tx][r]);
}

// ---------------- row stats: xb (bf16 copy) + sq (sum of squares) ----------
__global__ void rowstat(const float* __restrict__ x, ushort* __restrict__ xb, float* __restrict__ sq) {
    int row = blockIdx.x;
    const float* xr = x + (size_t)row * 768;
    ushort* xbr = xb + (size_t)row * 768;
    int t = threadIdx.x;
    float s = 0.f;
    #pragma unroll
    for (int i = 0; i < 3; ++i) {
        float vv = xr[t + i * 256];
        xbr[t + i * 256] = f2bf(vv);
        s += vv * vv;
    }
    #pragma unroll
    for (int off = 1; off < 64; off <<= 1) s += __shfl_xor(s, off);
    __shared__ float wsum[4];
    if ((t & 63) == 0) wsum[t >> 6] = s;
    __syncthreads();
    if (t == 0) sq[row] = wsum[0] + wsum[1] + wsum[2] + wsum[3];
}

// ---------------- fold dp/se_w1 into rank-1 vectors ------------------------
__global__ void precomp_ac(const float* __restrict__ dp_w, const float* __restrict__ dp_b,
                           const float* __restrict__ se_w1, const float* __restrict__ se_b1,
                           float* __restrict__ Avec, float* __restrict__ Cvec) {
    int o = blockIdx.x * 256 + threadIdx.x;  // grid 3 -> 768
    float a = 0.f, c = 0.f;
    for (int i = 0; i < 192; ++i) {
        float w = se_w1[(size_t)i * 768 + o];
        a += dp_w[i] * w;
        c += dp_b[i] * w;
    }
    Avec[o] = a;
    Cvec[o] = c + se_b1[o];
}

// ---------------- spatial h generation (rank-1 + gelu) ---------------------
__global__ void hgen(const float* __restrict__ mean_acc, const float* __restrict__ Avec,
                     const float* __restrict__ Cvec, ushort* __restrict__ h) {
    int row = blockIdx.x;
    float md = mean_acc[row] * (1.f / 1024.f);
    int t = threadIdx.x;
    #pragma unroll
    for (int i = 0; i < 3; ++i) {
        int o = t + i * 256;
        h[(size_t)row * 768 + o] = f2bf(gelu_f(md * Avec[o] + Cvec[o]));
    }
}

// ---------------- layernorm fp32 -> bf16 -----------------------------------
__global__ void lnorm(const float* __restrict__ xin, const float* __restrict__ g,
                      const float* __restrict__ b, ushort* __restrict__ xn) {
    int row = blockIdx.x;
    const float* xr = xin + (size_t)row * 768;
    int t = threadIdx.x;
    float v[3];
    float s = 0.f, s2 = 0.f;
    #pragma unroll
    for (int i = 0; i < 3; ++i) {
        v[i] = xr[t + i * 256];
        s += v[i];
        s2 += v[i] * v[i];
    }
    #pragma unroll
    for (int off = 1; off < 64; off <<= 1) { s += __shfl_xor(s, off); s2 += __shfl_xor(s2, off); }
    __shared__ float a0[4], a1[4];
    if ((t & 63) == 0) { a0[t >> 6] = s; a1[t >> 6] = s2; }
    __syncthreads();
    s = a0[0] + a0[1] + a0[2] + a0[3];
    s2 = a1[0] + a1[1] + a1[2] + a1[3];
    float mu = s * (1.f / 768.f);
    float var = s2 * (1.f / 768.f) - mu * mu;
    float rs = rsqrtf(var + 1e-5f);
    #pragma unroll
    for (int i = 0; i < 3; ++i) {
        int o = t + i * 256;
        xn[(size_t)row * 768 + o] = f2bf((v[i] - mu) * rs * g[o] + b[o]);
    }
}

// ---------------- MFMA GEMM: C = A[M,K] * Bt[N,K]^T ------------------------
#define BM 128
#define BN 128
#define BK 32

enum { EPI_BF16 = 0, EPI_GELU = 1, EPI_RES = 2, EPI_GRAM = 3 };

template <int EPI>
__launch_bounds__(256, 2)
__global__ void gemm_bt(const ushort* __restrict__ A, const ushort* __restrict__ Bt,
                        int M, int N, int K,
                        const float* __restrict__ bias,
                        const float* res, float* outf,
                        ushort* __restrict__ outh,
                        const float* __restrict__ sq, float* __restrict__ mean_acc) {
    __shared__ __align__(16) ushort As[2][BM * BK];
    __shared__ __align__(16) ushort Bs[2][BM * BK];

    int m0 = blockIdx.x * BM;
    int n0 = blockIdx.y * BN;
    if (EPI == EPI_GRAM) {
        int z = blockIdx.z;
        A += (size_t)z * 1024 * 768;
        Bt = A;
        sq += z * 1024;
        mean_acc += z * 1024;
    }
    int t = threadIdx.x, w = t >> 6, l = t & 63;
    int lg = l >> 4, li = l & 15;
    int wm = (w >> 1) * 64, wn = (w & 1) * 64;

    // staging: wave w loads chunks 2w, 2w+1 of A and B tiles (16 rows x 32 cols each)
    int srow = l >> 2, scol = (l & 3) * 8;
    const ushort* agp0 = A + (size_t)(m0 + (2 * w) * 16 + srow) * K + scol;
    const ushort* agp1 = A + (size_t)(m0 + (2 * w + 1) * 16 + srow) * K + scol;
    const ushort* bgp0 = Bt + (size_t)(n0 + (2 * w) * 16 + srow) * K + scol;
    const ushort* bgp1 = Bt + (size_t)(n0 + (2 * w + 1) * 16 + srow) * K + scol;
    ushort* la0 = &As[0][(2 * w) * 16 * BK];
    ushort* lb0 = &Bs[0][(2 * w) * 16 * BK];

    f32x4 acc[4][4] = {};

    auto stage = [&](int buf, int kt) {
        size_t ko = (size_t)kt * BK;
        ushort* la = la0 + buf * (BM * BK);
        ushort* lb = lb0 + buf * (BM * BK);
        __builtin_amdgcn_global_load_lds((const __attribute__((address_space(1))) void*)(agp0 + ko),
                                         (__attribute__((address_space(3))) void*)la, 16, 0, 0);
        __builtin_amdgcn_global_load_lds((const __attribute__((address_space(1))) void*)(agp1 + ko),
                                         (__attribute__((address_space(3))) void*)(la + 16 * BK), 16, 0, 0);
        __builtin_amdgcn_global_load_lds((const __attribute__((address_space(1))) void*)(bgp0 + ko),
                                         (__attribute__((address_space(3))) void*)lb, 16, 0, 0);
        __builtin_amdgcn_global_load_lds((const __attribute__((address_space(1))) void*)(bgp1 + ko),
                                         (__attribute__((address_space(3))) void*)(lb + 16 * BK), 16, 0, 0);
    };

    int nk = K / BK;
    stage(0, 0);
    __syncthreads();
    int buf = 0;
    for (int kt = 0; kt < nk; ++kt) {
        if (kt + 1 < nk) stage(buf ^ 1, kt + 1);
        bf16x8 af[4], bfr[4];
        #pragma unroll
        for (int i = 0; i < 4; ++i) {
            af[i] = *reinterpret_cast<const bf16x8*>(&As[buf][(wm + i * 16 + li) * BK + lg * 8]);
            bfr[i] = *reinterpret_cast<const bf16x8*>(&Bs[buf][(wn + i * 16 + li) * BK + lg * 8]);
        }
        #pragma unroll
        for (int mi = 0; mi < 4; ++mi)
            #pragma unroll
            for (int ni = 0; ni < 4; ++ni)
                acc[mi][ni] = __builtin_amdgcn_mfma_f32_16x16x32_bf16(af[mi], bfr[ni], acc[mi][ni], 0, 0, 0);
        __syncthreads();
        buf ^= 1;
    }

    // epilogue; C/D layout: col = lane&15, row = (lane>>4)*4 + reg
    #pragma unroll
    for (int mi = 0; mi < 4; ++mi) {
        #pragma unroll
        for (int r = 0; r < 4; ++r) {
            int row = m0 + wm + mi * 16 + lg * 4 + r;
            if (EPI == EPI_GRAM) {
                float si = sq[row];
                float s = 0.f;
                #pragma unroll
                for (int ni = 0; ni < 4; ++ni) {
                    int col = n0 + wn + ni * 16 + li;
                    float d2 = si + sq[col] - 2.f * acc[mi][ni][r];
                    s += sqrtf(fmaxf(d2, 0.f));
                }
                s += __shfl_xor(s, 1); s += __shfl_xor(s, 2);
                s += __shfl_xor(s, 4); s += __shfl_xor(s, 8);
                if (li == 0) atomicAdd(&mean_acc[row], s);
            } else {
                #pragma unroll
                for (int ni = 0; ni < 4; ++ni) {
                    int col = n0 + wn + ni * 16 + li;
                    float v = acc[mi][ni][r] + bias[col];
                    if (EPI == EPI_BF16) outh[(size_t)row * N + col] = f2bf(v);
                    if (EPI == EPI_GELU) outh[(size_t)row * N + col] = f2bf(gelu_f(v));
                    if (EPI == EPI_RES) outf[(size_t)row * N + col] = res[(size_t)row * N + col] + v;
                }
            }
        }
    }
}

// ---------------- flash attention: 12 heads, dh=64, N=1024 -----------------
__launch_bounds__(256, 2)
__global__ void flash_attn(const ushort* __restrict__ q, const ushort* __restrict__ k,
                           const ushort* __restrict__ v, ushort* __restrict__ o) {
    int qt = blockIdx.x, h = blockIdx.y, b = blockIdx.z;
    int t = threadIdx.x, w = t >> 6, l = t & 63;
    int lg = l >> 4, li = l & 15;

    __shared__ __align__(16) ushort Vt[64][40];   // V^T tile, padded rows (80B)
    __shared__ __align__(16) ushort P[4][16][40]; // per-wave P tile

    const size_t hoff = (size_t)h * 64;
    const size_t bbase = (size_t)b * 1024 * 768;

    int qrow = qt * 64 + w * 16 + li;
    bf16x8 q0 = *reinterpret_cast<const bf16x8*>(&q[bbase + (size_t)qrow * 768 + hoff + lg * 8]);
    bf16x8 q1 = *reinterpret_cast<const bf16x8*>(&q[bbase + (size_t)qrow * 768 + hoff + 32 + lg * 8]);

    float m_[4], ell[4];
    f32x4 oacc[4];
    #pragma unroll
    for (int r = 0; r < 4; ++r) { m_[r] = -1e30f; ell[r] = 0.f; }
    #pragma unroll
    for (int n = 0; n < 4; ++n) oacc[n] = f32x4{0.f, 0.f, 0.f, 0.f};

    int jv = t >> 3;         // 0..31: V row within tile (staging)
    int dg = (t & 7) * 8;    // d group (staging)

    for (int jt = 0; jt < 32; ++jt) {
        int j0 = jt * 32;
        __syncthreads();  // prev Vt reads complete
        {   // stage V^T tile
            const ushort* vp = &v[bbase + (size_t)(j0 + jv) * 768 + hoff + dg];
            ushort8 vv = *reinterpret_cast<const ushort8*>(vp);
            #pragma unroll
            for (int i = 0; i < 8; ++i) Vt[dg + i][jv] = vv[i];
        }
        // S = Q K^T / 8 for two 16-col j subtiles
        f32x4 s[2];
        #pragma unroll
        for (int jj = 0; jj < 2; ++jj) {
            int jrow = j0 + jj * 16 + li;
            bf16x8 kf0 = *reinterpret_cast<const bf16x8*>(&k[bbase + (size_t)jrow * 768 + hoff + lg * 8]);
            bf16x8 kf1 = *reinterpret_cast<const bf16x8*>(&k[bbase + (size_t)jrow * 768 + hoff + 32 + lg * 8]);
            f32x4 a = {0.f, 0.f, 0.f, 0.f};
            a = __builtin_amdgcn_mfma_f32_16x16x32_bf16(q0, kf0, a, 0, 0, 0);
            a = __builtin_amdgcn_mfma_f32_16x16x32_bf16(q1, kf1, a, 0, 0, 0);
            s[jj] = a * 0.125f;
        }
        // online softmax (row = q = lg*4+r; cols spread over 16 lanes)
        float mt[4];
        #pragma unroll
        for (int r = 0; r < 4; ++r) mt[r] = fmaxf(s[0][r], s[1][r]);
        #pragma unroll
        for (int r = 0; r < 4; ++r) {
            mt[r] = fmaxf(mt[r], __shfl_xor(mt[r], 1));
            mt[r] = fmaxf(mt[r], __shfl_xor(mt[r], 2));
            mt[r] = fmaxf(mt[r], __shfl_xor(mt[r], 4));
            mt[r] = fmaxf(mt[r], __shfl_xor(mt[r], 8));
        }
        float al[4], ps[4];
        #pragma unroll
        for (int r = 0; r < 4; ++r) {
            float mn = fmaxf(m_[r], mt[r]);
            al[r] = __expf(m_[r] - mn);
            m_[r] = mn;
            float p0 = __expf(s[0][r] - mn);
            float p1 = __expf(s[1][r] - mn);
            s[0][r] = p0; s[1][r] = p1;
            ps[r] = p0 + p1;
        }
        #pragma unroll
        for (int r = 0; r < 4; ++r) {
            ps[r] += __shfl_xor(ps[r], 1); ps[r] += __shfl_xor(ps[r], 2);
            ps[r] += __shfl_xor(ps[r], 4); ps[r] += __shfl_xor(ps[r], 8);
            ell[r] = ell[r] * al[r] + ps[r];
        }
        #pragma unroll
        for (int n = 0; n < 4; ++n)
            #pragma unroll
            for (int r = 0; r < 4; ++r) oacc[n][r] *= al[r];
        // write P (bf16) to per-wave LDS: P[q][j]
        #pragma unroll
        for (int jj = 0; jj < 2; ++jj)
            #pragma unroll
            for (int r = 0; r < 4; ++r)
                P[w][lg * 4 + r][jj * 16 + li] = f2bf(s[jj][r]);
        __syncthreads();  // Vt staged + P visible
        // PV: O += P[16x32] @ V[32x64]
        bf16x8 pf = *reinterpret_cast<const bf16x8*>(&P[w][li][lg * 8]);
        #pragma unroll
        for (int n = 0; n < 4; ++n) {
            bf16x8 vf = *reinterpret_cast<const bf16x8*>(&Vt[n * 16 + li][lg * 8]);
            oacc[n] = __builtin_amdgcn_mfma_f32_16x16x32_bf16(pf, vf, oacc[n], 0, 0, 0);
        }
    }
    #pragma unroll
    for (int n = 0; n < 4; ++n)
        #pragma unroll
        for (int r = 0; r < 4; ++r) {
            int row = qt * 64 + w * 16 + lg * 4 + r;
            o[bbase + (size_t)row * 768 + hoff + n * 16 + li] = f2bf(oacc[n][r] / ell[r]);
        }
}

// ---------------------------------------------------------------------------
extern "C" void kernel_launch(void* const* d_in, const int* in_sizes, int n_in,
                              void* d_out, int out_size, void* d_ws, size_t ws_size,
                              hipStream_t stream) {
    const float* x = (const float*)d_in[0];
    const float* dp_w = (const float*)d_in[1];
    const float* dp_b = (const float*)d_in[2];
    const float* se_w1 = (const float*)d_in[3];
    const float* se_b1 = (const float*)d_in[4];
    const float* se_w2 = (const float*)d_in[5];
    const float* se_b2 = (const float*)d_in[6];
    const float* wq = (const float*)d_in[7];  const float* bq = (const float*)d_in[8];
    const float* wk = (const float*)d_in[9];  const float* bk = (const float*)d_in[10];
    const float* wv = (const float*)d_in[11]; const float* bv = (const float*)d_in[12];
    const float* wo = (const float*)d_in[13]; const float* bo = (const float*)d_in[14];
    const float* gw1 = (const float*)d_in[15]; const float* gb1 = (const float*)d_in[16];
    const float* gw2 = (const float*)d_in[17]; const float* gb2 = (const float*)d_in[18];
    const float* n1g = (const float*)d_in[19]; const float* n1b = (const float*)d_in[20];
    const float* n2g = (const float*)d_in[21]; const float* n2b = (const float*)d_in[22];
    float* out = (float*)d_out;

    constexpr size_t SZ_ACT = (size_t)8192 * 768 * 2;  // 12,582,912 B
    char* W = (char*)d_ws;
    ushort* xb = (ushort*)(W);                  // bf16 x; later reused as xn
    ushort* q_ = (ushort*)(W + SZ_ACT);
    ushort* k_ = (ushort*)(W + 2 * SZ_ACT);
    ushort* v_ = (ushort*)(W + 3 * SZ_ACT);
    ushort* o_ = (ushort*)(W + 4 * SZ_ACT);
    ushort* hsp = q_;                           // spatial h (before q is live)
    ushort* hff = q_;                           // FFN hidden (50 MB spans q..o)
    ushort* wqt = (ushort*)(W + 5 * SZ_ACT);
    ushort* wkt = wqt + (size_t)768 * 768;
    ushort* wvt = wkt + (size_t)768 * 768;
    ushort* wot = wvt + (size_t)768 * 768;
    ushort* sw2t = wot + (size_t)768 * 768;
    ushort* g1t = sw2t + (size_t)768 * 768;
    ushort* g2t = g1t + (size_t)768 * 3072;
    float* sqv = (float*)(g2t + (size_t)3072 * 768);
    float* meanv = sqv + 8192;
    float* Avec = meanv + 8192;
    float* Cvec = Avec + 768;

    dim3 tb(32, 8);
    transpose_to_bf16<<<dim3(24, 24), tb, 0, stream>>>(se_w2, sw2t, 768, 768);
    transpose_to_bf16<<<dim3(24, 24), tb, 0, stream>>>(wq, wqt, 768, 768);
    transpose_to_bf16<<<dim3(24, 24), tb, 0, stream>>>(wk, wkt, 768, 768);
    transpose_to_bf16<<<dim3(24, 24), tb, 0, stream>>>(wv, wvt, 768, 768);
    transpose_to_bf16<<<dim3(24, 24), tb, 0, stream>>>(wo, wot, 768, 768);
    transpose_to_bf16<<<dim3(24, 96), tb, 0, stream>>>(gw1, g1t, 768, 3072);
    transpose_to_bf16<<<dim3(96, 24), tb, 0, stream>>>(gw2, g2t, 3072, 768);

    rowstat<<<8192, 256, 0, stream>>>(x, xb, sqv);
    precomp_ac<<<3, 256, 0, stream>>>(dp_w, dp_b, se_w1, se_b1, Avec, Cvec);
    hipMemsetAsync(meanv, 0, 8192 * sizeof(float), stream);

    // Gram -> distance row-sums
    gemm_bt<EPI_GRAM><<<dim3(8, 8, 8), 256, 0, stream>>>(xb, xb, 1024, 1024, 768,
                                                         nullptr, nullptr, nullptr, nullptr, sqv, meanv);
    hgen<<<8192, 256, 0, stream>>>(meanv, Avec, Cvec, hsp);
    // x = x + h @ se_w2 + se_b2  -> d_out (fp32 residual stream)
    gemm_bt<EPI_RES><<<dim3(64, 6), 256, 0, stream>>>(hsp, sw2t, 8192, 768, 768,
                                                      se_b2, x, out, nullptr, nullptr, nullptr);
    // attention block
    lnorm<<<8192, 256, 0, stream>>>(out, n1g, n1b, xb);
    gemm_bt<EPI_BF16><<<dim3(64, 6), 256, 0, stream>>>(xb, wqt, 8192, 768, 768,
                                                       bq, nullptr, nullptr, q_, nullptr, nullptr);
    gemm_bt<EPI_BF16><<<dim3(64, 6), 256, 0, stream>>>(xb, wkt, 8192, 768, 768,
                                                       bk, nullptr, nullptr, k_, nullptr, nullptr);
    gemm_bt<EPI_BF16><<<dim3(64, 6), 256, 0, stream>>>(xb, wvt, 8192, 768, 768,
                                                       bv, nullptr, nullptr, v_, nullptr, nullptr);
    flash_attn<<<dim3(16, 12, 8), 256, 0, stream>>>(q_, k_, v_, o_);
    gemm_bt<EPI_RES><<<dim3(64, 6), 256, 0, stream>>>(o_, wot, 8192, 768, 768,
                                                      bo, out, out, nullptr, nullptr, nullptr);
    // FFN block
    lnorm<<<8192, 256, 0, stream>>>(out, n2g, n2b, xb);
    gemm_bt<EPI_GELU><<<dim3(64, 24), 256, 0, stream>>>(xb, g1t, 8192, 3072, 768,
                                                        gb1, nullptr, nullptr, hff, nullptr, nullptr);
    gemm_bt<EPI_RES><<<dim3(64, 6), 256, 0, stream>>>(hff, g2t, 8192, 768, 3072,
                                                      gb2, out, out, nullptr, nullptr, nullptr);
}

// Round 2
// 513.329 us; speedup vs baseline: 1.0156x; 1.0156x over previous
//
#include <hip/hip_runtime.h>
#include <hip/hip_bf16.h>

typedef unsigned short ushort;
typedef __attribute__((ext_vector_type(8))) __bf16 bf16x8;
typedef __attribute__((ext_vector_type(4))) float f32x4;
typedef __attribute__((ext_vector_type(8))) ushort ushort8;

__device__ inline ushort f2bf(float f) {
    union { float f; unsigned u; } a{f};
    unsigned r = a.u + 0x7FFFu + ((a.u >> 16) & 1u);
    return (ushort)(r >> 16);
}
__device__ inline float gelu_f(float x) {
    return 0.5f * x * (1.f + erff(x * 0.70710678118654752f));
}

// ---------------- transpose weight [K,N] fp32 -> [N,K] bf16 ----------------
__global__ void transpose_to_bf16(const float* __restrict__ Wm, ushort* __restrict__ Wt, int K, int N) {
    __shared__ float tile[32][33];
    int k0 = blockIdx.x * 32, n0 = blockIdx.y * 32;
    int tx = threadIdx.x, ty = threadIdx.y;
    #pragma unroll
    for (int r = ty; r < 32; r += 8) tile[r][tx] = Wm[(size_t)(k0 + r) * N + n0 + tx];
    __syncthreads();
    #pragma unroll
    for (int r = ty; r < 32; r += 8) Wt[(size_t)(n0 + r) * K + k0 + tx] = f2bf(tile[tx][r]);
}

// ---------------- row stats: xb (bf16 copy) + sq (sum of squares) ----------
__global__ void rowstat(const float* __restrict__ x, ushort* __restrict__ xb, float* __restrict__ sq) {
    int row = blockIdx.x;
    const float* xr = x + (size_t)row * 768;
    ushort* xbr = xb + (size_t)row * 768;
    int t = threadIdx.x;
    float s = 0.f;
    #pragma unroll
    for (int i = 0; i < 3; ++i) {
        float vv = xr[t + i * 256];
        xbr[t + i * 256] = f2bf(vv);
        s += vv * vv;
    }
    #pragma unroll
    for (int off = 1; off < 64; off <<= 1) s += __shfl_xor(s, off);
    __shared__ float wsum[4];
    if ((t & 63) == 0) wsum[t >> 6] = s;
    __syncthreads();
    if (t == 0) sq[row] = wsum[0] + wsum[1] + wsum[2] + wsum[3];
}

// ---------------- fold dp/se_w1 into rank-1 vectors ------------------------
__global__ void precomp_ac(const float* __restrict__ dp_w, const float* __restrict__ dp_b,
                           const float* __restrict__ se_w1, const float* __restrict__ se_b1,
                           float* __restrict__ Avec, float* __restrict__ Cvec) {
    int o = blockIdx.x * 256 + threadIdx.x;  // grid 3 -> 768
    float a = 0.f, c = 0.f;
    for (int i = 0; i < 192; ++i) {
        float w = se_w1[(size_t)i * 768 + o];
        a += dp_w[i] * w;
        c += dp_b[i] * w;
    }
    Avec[o] = a;
    Cvec[o] = c + se_b1[o];
}

// ---------------- spatial h generation (rank-1 + gelu) ---------------------
__global__ void hgen(const float* __restrict__ mean_acc, const float* __restrict__ Avec,
                     const float* __restrict__ Cvec, ushort* __restrict__ h) {
    int row = blockIdx.x;
    float md = mean_acc[row] * (1.f / 1024.f);
    int t = threadIdx.x;
    #pragma unroll
    for (int i = 0; i < 3; ++i) {
        int o = t + i * 256;
        h[(size_t)row * 768 + o] = f2bf(gelu_f(md * Avec[o] + Cvec[o]));
    }
}

// ---------------- layernorm fp32 -> bf16 -----------------------------------
__global__ void lnorm(const float* __restrict__ xin, const float* __restrict__ g,
                      const float* __restrict__ b, ushort* __restrict__ xn) {
    int row = blockIdx.x;
    const float* xr = xin + (size_t)row * 768;
    int t = threadIdx.x;
    float v[3];
    float s = 0.f, s2 = 0.f;
    #pragma unroll
    for (int i = 0; i < 3; ++i) {
        v[i] = xr[t + i * 256];
        s += v[i];
        s2 += v[i] * v[i];
    }
    #pragma unroll
    for (int off = 1; off < 64; off <<= 1) { s += __shfl_xor(s, off); s2 += __shfl_xor(s2, off); }
    __shared__ float a0[4], a1[4];
    if ((t & 63) == 0) { a0[t >> 6] = s; a1[t >> 6] = s2; }
    __syncthreads();
    s = a0[0] + a0[1] + a0[2] + a0[3];
    s2 = a1[0] + a1[1] + a1[2] + a1[3];
    float mu = s * (1.f / 768.f);
    float var = s2 * (1.f / 768.f) - mu * mu;
    float rs = rsqrtf(var + 1e-5f);
    #pragma unroll
    for (int i = 0; i < 3; ++i) {
        int o = t + i * 256;
        xn[(size_t)row * 768 + o] = f2bf((v[i] - mu) * rs * g[o] + b[o]);
    }
}

// ---------------- MFMA GEMM: C = A[M,K] * Bt[N,K]^T ------------------------
#define BM 128
#define BN 128
#define BK 32

enum { EPI_BF16 = 0, EPI_GELU = 1, EPI_RES = 2, EPI_GRAM = 3 };

template <int EPI>
__launch_bounds__(256, 2)
__global__ void gemm_bt(const ushort* __restrict__ A, const ushort* __restrict__ Bt,
                        int M, int N, int K,
                        const float* __restrict__ bias,
                        const float* res, float* outf,
                        ushort* __restrict__ outh,
                        const float* __restrict__ sq, float* __restrict__ mean_acc) {
    __shared__ __align__(16) ushort As[2][BM * BK];
    __shared__ __align__(16) ushort Bs[2][BM * BK];

    int m0 = blockIdx.x * BM;
    int n0 = blockIdx.y * BN;
    if (EPI == EPI_GRAM) {
        int z = blockIdx.z;
        A += (size_t)z * 1024 * 768;
        Bt = A;
        sq += z * 1024;
        mean_acc += z * 1024;
    }
    int t = threadIdx.x, w = t >> 6, l = t & 63;
    int lg = l >> 4, li = l & 15;
    int wm = (w >> 1) * 64, wn = (w & 1) * 64;

    // staging: wave w loads chunks 2w, 2w+1 of A and B tiles (16 rows x 32 cols each)
    int srow = l >> 2, scol = (l & 3) * 8;
    const ushort* agp0 = A + (size_t)(m0 + (2 * w) * 16 + srow) * K + scol;
    const ushort* agp1 = A + (size_t)(m0 + (2 * w + 1) * 16 + srow) * K + scol;
    const ushort* bgp0 = Bt + (size_t)(n0 + (2 * w) * 16 + srow) * K + scol;
    const ushort* bgp1 = Bt + (size_t)(n0 + (2 * w + 1) * 16 + srow) * K + scol;
    ushort* la0 = &As[0][(2 * w) * 16 * BK];
    ushort* lb0 = &Bs[0][(2 * w) * 16 * BK];

    f32x4 acc[4][4] = {};

    auto stage = [&](int buf, int kt) {
        size_t ko = (size_t)kt * BK;
        ushort* la = la0 + buf * (BM * BK);
        ushort* lb = lb0 + buf * (BM * BK);
        __builtin_amdgcn_global_load_lds((const __attribute__((address_space(1))) void*)(agp0 + ko),
                                         (__attribute__((address_space(3))) void*)la, 16, 0, 0);
        __builtin_amdgcn_global_load_lds((const __attribute__((address_space(1))) void*)(agp1 + ko),
                                         (__attribute__((address_space(3))) void*)(la + 16 * BK), 16, 0, 0);
        __builtin_amdgcn_global_load_lds((const __attribute__((address_space(1))) void*)(bgp0 + ko),
                                         (__attribute__((address_space(3))) void*)lb, 16, 0, 0);
        __builtin_amdgcn_global_load_lds((const __attribute__((address_space(1))) void*)(bgp1 + ko),
                                         (__attribute__((address_space(3))) void*)(lb + 16 * BK), 16, 0, 0);
    };

    int nk = K / BK;
    stage(0, 0);
    __syncthreads();
    int buf = 0;
    for (int kt = 0; kt < nk; ++kt) {
        if (kt + 1 < nk) stage(buf ^ 1, kt + 1);
        bf16x8 af[4], bfr[4];
        #pragma unroll
        for (int i = 0; i < 4; ++i) {
            af[i] = *reinterpret_cast<const bf16x8*>(&As[buf][(wm + i * 16 + li) * BK + lg * 8]);
            bfr[i] = *reinterpret_cast<const bf16x8*>(&Bs[buf][(wn + i * 16 + li) * BK + lg * 8]);
        }
        #pragma unroll
        for (int mi = 0; mi < 4; ++mi)
            #pragma unroll
            for (int ni = 0; ni < 4; ++ni)
                acc[mi][ni] = __builtin_amdgcn_mfma_f32_16x16x32_bf16(af[mi], bfr[ni], acc[mi][ni], 0, 0, 0);
        __syncthreads();
        buf ^= 1;
    }

    // epilogue; C/D layout: col = lane&15, row = (lane>>4)*4 + reg
    #pragma unroll
    for (int mi = 0; mi < 4; ++mi) {
        #pragma unroll
        for (int r = 0; r < 4; ++r) {
            int row = m0 + wm + mi * 16 + lg * 4 + r;
            if (EPI == EPI_GRAM) {
                float si = sq[row];
                float s = 0.f;
                #pragma unroll
                for (int ni = 0; ni < 4; ++ni) {
                    int col = n0 + wn + ni * 16 + li;
                    float d2 = si + sq[col] - 2.f * acc[mi][ni][r];
                    s += sqrtf(fmaxf(d2, 0.f));
                }
                s += __shfl_xor(s, 1); s += __shfl_xor(s, 2);
                s += __shfl_xor(s, 4); s += __shfl_xor(s, 8);
                if (li == 0) atomicAdd(&mean_acc[row], s);
            } else {
                #pragma unroll
                for (int ni = 0; ni < 4; ++ni) {
                    int col = n0 + wn + ni * 16 + li;
                    float v = acc[mi][ni][r] + bias[col];
                    if (EPI == EPI_BF16) outh[(size_t)row * N + col] = f2bf(v);
                    if (EPI == EPI_GELU) outh[(size_t)row * N + col] = f2bf(gelu_f(v));
                    if (EPI == EPI_RES) outf[(size_t)row * N + col] = res[(size_t)row * N + col] + v;
                }
            }
        }
    }
}

// ---------------- flash attention v2: KVBLK=64, conflict-free LDS ----------
// grid (16, 12, 8); 4 waves; wave w owns q-rows [qt*64+w*16, +16)
__launch_bounds__(256, 3)
__global__ void flash_attn(const ushort* __restrict__ q, const ushort* __restrict__ k,
                           const ushort* __restrict__ v, ushort* __restrict__ o) {
    int qt = blockIdx.x, h = blockIdx.y, b = blockIdx.z;
    int t = threadIdx.x, w = t >> 6, l = t & 63;
    int lg = l >> 4, li = l & 15;

    // Vt[buf][d][kv]: stride 72 elem = 144 B (16B-aligned rows, bank-spread)
    __shared__ __align__(16) ushort Vt[2][64][72];
    __shared__ __align__(16) ushort P[4][16][72];  // per-wave P[q][kv]

    const size_t hoff = (size_t)h * 64;
    const size_t bbase = (size_t)b * 1024 * 768;

    int qrow = qt * 64 + w * 16 + li;
    const ushort* qp = &q[bbase + (size_t)qrow * 768 + hoff];
    bf16x8 q0 = *reinterpret_cast<const bf16x8*>(qp + lg * 8);
    bf16x8 q1 = *reinterpret_cast<const bf16x8*>(qp + 32 + lg * 8);

    float m_[4], ell[4];
    f32x4 oacc[4];
    #pragma unroll
    for (int r = 0; r < 4; ++r) { m_[r] = -1e30f; ell[r] = 0.f; }
    #pragma unroll
    for (int n = 0; n < 4; ++n) oacc[n] = f32x4{0.f, 0.f, 0.f, 0.f};

    // V staging: lane owns kv-row (t&63), d-chunks w and w+4 (8 elems each).
    // Writes go down a Vt column (fixed kv): bank = 4i + kv/2 -> conflict-free.
    int vrow = t & 63;
    int vc = t >> 6;  // chunk pair: vc, vc+4
    const ushort* vbase = &v[bbase + hoff];

    ushort8 vv0 = *reinterpret_cast<const ushort8*>(&vbase[(size_t)vrow * 768 + vc * 8]);
    ushort8 vv1 = *reinterpret_cast<const ushort8*>(&vbase[(size_t)vrow * 768 + (vc + 4) * 8]);

    for (int jt = 0; jt < 16; ++jt) {
        int j0 = jt * 64, buf = jt & 1;
        // write current V tile (loads issued one iteration ago)
        #pragma unroll
        for (int i = 0; i < 8; ++i) Vt[buf][vc * 8 + i][vrow] = vv0[i];
        #pragma unroll
        for (int i = 0; i < 8; ++i) Vt[buf][(vc + 4) * 8 + i][vrow] = vv1[i];
        // prefetch next V tile (hides HBM/L2 latency under S + softmax)
        if (jt < 15) {
            vv0 = *reinterpret_cast<const ushort8*>(&vbase[(size_t)(j0 + 64 + vrow) * 768 + vc * 8]);
            vv1 = *reinterpret_cast<const ushort8*>(&vbase[(size_t)(j0 + 64 + vrow) * 768 + (vc + 4) * 8]);
        }
        // S = Q K^T / 8 over 4 16-kv subtiles
        f32x4 s[4];
        #pragma unroll
        for (int jj = 0; jj < 4; ++jj) {
            const ushort* kp = &k[bbase + (size_t)(j0 + jj * 16 + li) * 768 + hoff];
            bf16x8 kf0 = *reinterpret_cast<const bf16x8*>(kp + lg * 8);
            bf16x8 kf1 = *reinterpret_cast<const bf16x8*>(kp + 32 + lg * 8);
            f32x4 a = {0.f, 0.f, 0.f, 0.f};
            a = __builtin_amdgcn_mfma_f32_16x16x32_bf16(q0, kf0, a, 0, 0, 0);
            a = __builtin_amdgcn_mfma_f32_16x16x32_bf16(q1, kf1, a, 0, 0, 0);
            s[jj] = a * 0.125f;
        }
        // online softmax; lane holds S[q=lg*4+r][kv=jj*16+li]
        float mt[4];
        #pragma unroll
        for (int r = 0; r < 4; ++r)
            mt[r] = fmaxf(fmaxf(s[0][r], s[1][r]), fmaxf(s[2][r], s[3][r]));
        #pragma unroll
        for (int r = 0; r < 4; ++r) {
            mt[r] = fmaxf(mt[r], __shfl_xor(mt[r], 1));
            mt[r] = fmaxf(mt[r], __shfl_xor(mt[r], 2));
            mt[r] = fmaxf(mt[r], __shfl_xor(mt[r], 4));
            mt[r] = fmaxf(mt[r], __shfl_xor(mt[r], 8));
        }
        float al[4], ps[4];
        #pragma unroll
        for (int r = 0; r < 4; ++r) {
            float mn = fmaxf(m_[r], mt[r]);
            al[r] = __expf(m_[r] - mn);
            m_[r] = mn;
            float p0 = __expf(s[0][r] - mn);
            float p1 = __expf(s[1][r] - mn);
            float p2 = __expf(s[2][r] - mn);
            float p3 = __expf(s[3][r] - mn);
            s[0][r] = p0; s[1][r] = p1; s[2][r] = p2; s[3][r] = p3;
            ps[r] = (p0 + p1) + (p2 + p3);
        }
        #pragma unroll
        for (int r = 0; r < 4; ++r) {
            ps[r] += __shfl_xor(ps[r], 1); ps[r] += __shfl_xor(ps[r], 2);
            ps[r] += __shfl_xor(ps[r], 4); ps[r] += __shfl_xor(ps[r], 8);
            ell[r] = ell[r] * al[r] + ps[r];
        }
        #pragma unroll
        for (int n = 0; n < 4; ++n)
            #pragma unroll
            for (int r = 0; r < 4; ++r) oacc[n][r] *= al[r];
        // P -> per-wave LDS (no barrier needed: same-wave LDS ops are in-order)
        #pragma unroll
        for (int jj = 0; jj < 4; ++jj)
            #pragma unroll
            for (int r = 0; r < 4; ++r)
                P[w][lg * 4 + r][jj * 16 + li] = f2bf(s[jj][r]);
        __syncthreads();  // Vt[buf] staged by all waves
        // PV: O += P[16x64] @ V[64x64]
        bf16x8 pf0 = *reinterpret_cast<const bf16x8*>(&P[w][li][lg * 8]);
        bf16x8 pf1 = *reinterpret_cast<const bf16x8*>(&P[w][li][32 + lg * 8]);
        #pragma unroll
        for (int n = 0; n < 4; ++n) {
            bf16x8 vf0 = *reinterpret_cast<const bf16x8*>(&Vt[buf][n * 16 + li][lg * 8]);
            bf16x8 vf1 = *reinterpret_cast<const bf16x8*>(&Vt[buf][n * 16 + li][32 + lg * 8]);
            oacc[n] = __builtin_amdgcn_mfma_f32_16x16x32_bf16(pf0, vf0, oacc[n], 0, 0, 0);
            oacc[n] = __builtin_amdgcn_mfma_f32_16x16x32_bf16(pf1, vf1, oacc[n], 0, 0, 0);
        }
    }
    #pragma unroll
    for (int n = 0; n < 4; ++n)
        #pragma unroll
        for (int r = 0; r < 4; ++r) {
            int row = qt * 64 + w * 16 + lg * 4 + r;
            o[bbase + (size_t)row * 768 + hoff + n * 16 + li] = f2bf(oacc[n][r] / ell[r]);
        }
}

// ---------------------------------------------------------------------------
extern "C" void kernel_launch(void* const* d_in, const int* in_sizes, int n_in,
                              void* d_out, int out_size, void* d_ws, size_t ws_size,
                              hipStream_t stream) {
    const float* x = (const float*)d_in[0];
    const float* dp_w = (const float*)d_in[1];
    const float* dp_b = (const float*)d_in[2];
    const float* se_w1 = (const float*)d_in[3];
    const float* se_b1 = (const float*)d_in[4];
    const float* se_w2 = (const float*)d_in[5];
    const float* se_b2 = (const float*)d_in[6];
    const float* wq = (const float*)d_in[7];  const float* bq = (const float*)d_in[8];
    const float* wk = (const float*)d_in[9];  const float* bk = (const float*)d_in[10];
    const float* wv = (const float*)d_in[11]; const float* bv = (const float*)d_in[12];
    const float* wo = (const float*)d_in[13]; const float* bo = (const float*)d_in[14];
    const float* gw1 = (const float*)d_in[15]; const float* gb1 = (const float*)d_in[16];
    const float* gw2 = (const float*)d_in[17]; const float* gb2 = (const float*)d_in[18];
    const float* n1g = (const float*)d_in[19]; const float* n1b = (const float*)d_in[20];
    const float* n2g = (const float*)d_in[21]; const float* n2b = (const float*)d_in[22];
    float* out = (float*)d_out;

    constexpr size_t SZ_ACT = (size_t)8192 * 768 * 2;  // 12,582,912 B
    char* W = (char*)d_ws;
    ushort* xb = (ushort*)(W);                  // bf16 x; later reused as xn
    ushort* q_ = (ushort*)(W + SZ_ACT);
    ushort* k_ = (ushort*)(W + 2 * SZ_ACT);
    ushort* v_ = (ushort*)(W + 3 * SZ_ACT);
    ushort* o_ = (ushort*)(W + 4 * SZ_ACT);
    ushort* hsp = q_;                           // spatial h (before q is live)
    ushort* hff = q_;                           // FFN hidden (50 MB spans q..o)
    ushort* wqt = (ushort*)(W + 5 * SZ_ACT);
    ushort* wkt = wqt + (size_t)768 * 768;
    ushort* wvt = wkt + (size_t)768 * 768;
    ushort* wot = wvt + (size_t)768 * 768;
    ushort* sw2t = wot + (size_t)768 * 768;
    ushort* g1t = sw2t + (size_t)768 * 768;
    ushort* g2t = g1t + (size_t)768 * 3072;
    float* sqv = (float*)(g2t + (size_t)3072 * 768);
    float* meanv = sqv + 8192;
    float* Avec = meanv + 8192;
    float* Cvec = Avec + 768;

    dim3 tb(32, 8);
    transpose_to_bf16<<<dim3(24, 24), tb, 0, stream>>>(se_w2, sw2t, 768, 768);
    transpose_to_bf16<<<dim3(24, 24), tb, 0, stream>>>(wq, wqt, 768, 768);
    transpose_to_bf16<<<dim3(24, 24), tb, 0, stream>>>(wk, wkt, 768, 768);
    transpose_to_bf16<<<dim3(24, 24), tb, 0, stream>>>(wv, wvt, 768, 768);
    transpose_to_bf16<<<dim3(24, 24), tb, 0, stream>>>(wo, wot, 768, 768);
    transpose_to_bf16<<<dim3(24, 96), tb, 0, stream>>>(gw1, g1t, 768, 3072);
    transpose_to_bf16<<<dim3(96, 24), tb, 0, stream>>>(gw2, g2t, 3072, 768);

    rowstat<<<8192, 256, 0, stream>>>(x, xb, sqv);
    precomp_ac<<<3, 256, 0, stream>>>(dp_w, dp_b, se_w1, se_b1, Avec, Cvec);
    hipMemsetAsync(meanv, 0, 8192 * sizeof(float), stream);

    // Gram -> distance row-sums
    gemm_bt<EPI_GRAM><<<dim3(8, 8, 8), 256, 0, stream>>>(xb, xb, 1024, 1024, 768,
                                                         nullptr, nullptr, nullptr, nullptr, sqv, meanv);
    hgen<<<8192, 256, 0, stream>>>(meanv, Avec, Cvec, hsp);
    // x = x + h @ se_w2 + se_b2  -> d_out (fp32 residual stream)
    gemm_bt<EPI_RES><<<dim3(64, 6), 256, 0, stream>>>(hsp, sw2t, 8192, 768, 768,
                                                      se_b2, x, out, nullptr, nullptr, nullptr);
    // attention block
    lnorm<<<8192, 256, 0, stream>>>(out, n1g, n1b, xb);
    gemm_bt<EPI_BF16><<<dim3(64, 6), 256, 0, stream>>>(xb, wqt, 8192, 768, 768,
                                                       bq, nullptr, nullptr, q_, nullptr, nullptr);
    gemm_bt<EPI_BF16><<<dim3(64, 6), 256, 0, stream>>>(xb, wkt, 8192, 768, 768,
                                                       bk, nullptr, nullptr, k_, nullptr, nullptr);
    gemm_bt<EPI_BF16><<<dim3(64, 6), 256, 0, stream>>>(xb, wvt, 8192, 768, 768,
                                                       bv, nullptr, nullptr, v_, nullptr, nullptr);
    flash_attn<<<dim3(16, 12, 8), 256, 0, stream>>>(q_, k_, v_, o_);
    gemm_bt<EPI_RES><<<dim3(64, 6), 256, 0, stream>>>(o_, wot, 8192, 768, 768,
                                                      bo, out, out, nullptr, nullptr, nullptr);
    // FFN block
    lnorm<<<8192, 256, 0, stream>>>(out, n2g, n2b, xb);
    gemm_bt<EPI_GELU><<<dim3(64, 24), 256, 0, stream>>>(xb, g1t, 8192, 3072, 768,
                                                        gb1, nullptr, nullptr, hff, nullptr, nullptr);
    gemm_bt<EPI_RES><<<dim3(64, 6), 256, 0, stream>>>(hff, g2t, 8192, 768, 3072,
                                                      gb2, out, out, nullptr, nullptr, nullptr);
}

// Round 3
// 469.472 us; speedup vs baseline: 1.1105x; 1.0934x over previous
//
#include <hip/hip_runtime.h>
#include <hip/hip_bf16.h>

typedef unsigned short ushort;
typedef __attribute__((ext_vector_type(8))) __bf16 bf16x8;
typedef __attribute__((ext_vector_type(4))) float f32x4;
typedef __attribute__((ext_vector_type(8))) ushort ushort8;

__device__ inline ushort f2bf(float f) {
    union { float f; unsigned u; } a{f};
    unsigned r = a.u + 0x7FFFu + ((a.u >> 16) & 1u);
    return (ushort)(r >> 16);
}
__device__ inline float gelu_f(float x) {
    return 0.5f * x * (1.f + erff(x * 0.70710678118654752f));
}

// ---------------- transpose weight [K,N] fp32 -> [N,K] bf16 ----------------
__global__ void transpose_to_bf16(const float* __restrict__ Wm, ushort* __restrict__ Wt, int K, int N) {
    __shared__ float tile[32][33];
    int k0 = blockIdx.x * 32, n0 = blockIdx.y * 32;
    int tx = threadIdx.x, ty = threadIdx.y;
    #pragma unroll
    for (int r = ty; r < 32; r += 8) tile[r][tx] = Wm[(size_t)(k0 + r) * N + n0 + tx];
    __syncthreads();
    #pragma unroll
    for (int r = ty; r < 32; r += 8) Wt[(size_t)(n0 + r) * K + k0 + tx] = f2bf(tile[tx][r]);
}

// ---------------- row stats: xb (bf16 copy) + sq (sum of squares) ----------
__global__ void rowstat(const float* __restrict__ x, ushort* __restrict__ xb, float* __restrict__ sq) {
    int row = blockIdx.x;
    const float* xr = x + (size_t)row * 768;
    ushort* xbr = xb + (size_t)row * 768;
    int t = threadIdx.x;
    float s = 0.f;
    #pragma unroll
    for (int i = 0; i < 3; ++i) {
        float vv = xr[t + i * 256];
        xbr[t + i * 256] = f2bf(vv);
        s += vv * vv;
    }
    #pragma unroll
    for (int off = 1; off < 64; off <<= 1) s += __shfl_xor(s, off);
    __shared__ float wsum[4];
    if ((t & 63) == 0) wsum[t >> 6] = s;
    __syncthreads();
    if (t == 0) sq[row] = wsum[0] + wsum[1] + wsum[2] + wsum[3];
}

// ---------------- fold dp/se_w1 into rank-1 vectors ------------------------
__global__ void precomp_ac(const float* __restrict__ dp_w, const float* __restrict__ dp_b,
                           const float* __restrict__ se_w1, const float* __restrict__ se_b1,
                           float* __restrict__ Avec, float* __restrict__ Cvec) {
    int o = blockIdx.x * 256 + threadIdx.x;  // grid 3 -> 768
    float a = 0.f, c = 0.f;
    for (int i = 0; i < 192; ++i) {
        float w = se_w1[(size_t)i * 768 + o];
        a += dp_w[i] * w;
        c += dp_b[i] * w;
    }
    Avec[o] = a;
    Cvec[o] = c + se_b1[o];
}

// ---------------- spatial h generation (rank-1 + gelu) ---------------------
__global__ void hgen(const float* __restrict__ mean_acc, const float* __restrict__ Avec,
                     const float* __restrict__ Cvec, ushort* __restrict__ h) {
    int row = blockIdx.x;
    float md = mean_acc[row] * (1.f / 1024.f);
    int t = threadIdx.x;
    #pragma unroll
    for (int i = 0; i < 3; ++i) {
        int o = t + i * 256;
        h[(size_t)row * 768 + o] = f2bf(gelu_f(md * Avec[o] + Cvec[o]));
    }
}

// ---------------- layernorm fp32 -> bf16 -----------------------------------
__global__ void lnorm(const float* __restrict__ xin, const float* __restrict__ g,
                      const float* __restrict__ b, ushort* __restrict__ xn) {
    int row = blockIdx.x;
    const float* xr = xin + (size_t)row * 768;
    int t = threadIdx.x;
    float v[3];
    float s = 0.f, s2 = 0.f;
    #pragma unroll
    for (int i = 0; i < 3; ++i) {
        v[i] = xr[t + i * 256];
        s += v[i];
        s2 += v[i] * v[i];
    }
    #pragma unroll
    for (int off = 1; off < 64; off <<= 1) { s += __shfl_xor(s, off); s2 += __shfl_xor(s2, off); }
    __shared__ float a0[4], a1[4];
    if ((t & 63) == 0) { a0[t >> 6] = s; a1[t >> 6] = s2; }
    __syncthreads();
    s = a0[0] + a0[1] + a0[2] + a0[3];
    s2 = a1[0] + a1[1] + a1[2] + a1[3];
    float mu = s * (1.f / 768.f);
    float var = s2 * (1.f / 768.f) - mu * mu;
    float rs = rsqrtf(var + 1e-5f);
    #pragma unroll
    for (int i = 0; i < 3; ++i) {
        int o = t + i * 256;
        xn[(size_t)row * 768 + o] = f2bf((v[i] - mu) * rs * g[o] + b[o]);
    }
}

// ---------------- MFMA GEMM: C = A[M,K] * Bt[N,K]^T ------------------------
#define BM 128
#define BK 32

enum { EPI_BF16 = 0, EPI_GELU = 1, EPI_RES = 2, EPI_GRAM = 3, EPI_QKV = 4 };

template <int EPI, int BNT>
__launch_bounds__(256, BNT == 64 ? 4 : 2)
__global__ void gemm_bt(const ushort* __restrict__ A, const ushort* __restrict__ Bt,
                        int M, int N, int K,
                        const float* __restrict__ bias,
                        const float* res, float* outf,
                        ushort* __restrict__ outh,
                        const float* __restrict__ sq, float* __restrict__ mean_acc) {
    __shared__ __align__(16) ushort As[2][BM * BK];
    __shared__ __align__(16) ushort Bs[2][BNT * BK];

    // XCD-chunked swizzle: co-locate consecutive work ids on one XCD
    unsigned gx = gridDim.x, gy = gridDim.y;
    unsigned flat = blockIdx.x + gx * (blockIdx.y + gy * blockIdx.z);
    unsigned total = gx * gy * gridDim.z;
    unsigned chunk = total >> 3;  // all launches have total % 8 == 0
    flat = (flat & 7) * chunk + (flat >> 3);
    unsigned bx = flat % gx;
    unsigned rem = flat / gx;
    unsigned by = rem % gy;
    unsigned bz = rem / gy;

    int m0 = bx * BM;
    int n0 = by * BNT;
    if (EPI == EPI_GRAM) {
        A += (size_t)bz * 1024 * 768;
        Bt = A;
        sq += bz * 1024;
        mean_acc += bz * 1024;
    }
    int t = threadIdx.x, w = t >> 6, l = t & 63;
    int lg = l >> 4, li = l & 15;
    constexpr int MI = (BNT == 128) ? 4 : 2;
    int wm = (BNT == 128) ? (w >> 1) * 64 : w * 32;
    int wn = (BNT == 128) ? (w & 1) * 64 : 0;

    // staging: each wave loads 16-row x 32-col chunks; lane l covers 16B at l*16B
    int srow = l >> 2, scol = (l & 3) * 8;
    const ushort* agp0 = A + (size_t)(m0 + (2 * w) * 16 + srow) * K + scol;
    const ushort* agp1 = A + (size_t)(m0 + (2 * w + 1) * 16 + srow) * K + scol;
    const ushort* bgp0;
    const ushort* bgp1 = nullptr;
    ushort* la0 = &As[0][(2 * w) * 16 * BK];
    ushort* lb0;
    if (BNT == 128) {
        bgp0 = Bt + (size_t)(n0 + (2 * w) * 16 + srow) * K + scol;
        bgp1 = Bt + (size_t)(n0 + (2 * w + 1) * 16 + srow) * K + scol;
        lb0 = &Bs[0][(2 * w) * 16 * BK];
    } else {
        bgp0 = Bt + (size_t)(n0 + w * 16 + srow) * K + scol;
        lb0 = &Bs[0][w * 16 * BK];
    }

    f32x4 acc[MI][4] = {};

    auto stage = [&](int buf, int kt) {
        size_t ko = (size_t)kt * BK;
        ushort* la = la0 + buf * (BM * BK);
        ushort* lb = lb0 + buf * (BNT * BK);
        __builtin_amdgcn_global_load_lds((const __attribute__((address_space(1))) void*)(agp0 + ko),
                                         (__attribute__((address_space(3))) void*)la, 16, 0, 0);
        __builtin_amdgcn_global_load_lds((const __attribute__((address_space(1))) void*)(agp1 + ko),
                                         (__attribute__((address_space(3))) void*)(la + 16 * BK), 16, 0, 0);
        __builtin_amdgcn_global_load_lds((const __attribute__((address_space(1))) void*)(bgp0 + ko),
                                         (__attribute__((address_space(3))) void*)lb, 16, 0, 0);
        if (BNT == 128)
            __builtin_amdgcn_global_load_lds((const __attribute__((address_space(1))) void*)(bgp1 + ko),
                                             (__attribute__((address_space(3))) void*)(lb + 16 * BK), 16, 0, 0);
    };

    int nk = K / BK;
    stage(0, 0);
    __syncthreads();
    int buf = 0;
    for (int kt = 0; kt < nk; ++kt) {
        if (kt + 1 < nk) stage(buf ^ 1, kt + 1);
        bf16x8 af[MI], bfr[4];
        #pragma unroll
        for (int i = 0; i < MI; ++i)
            af[i] = *reinterpret_cast<const bf16x8*>(&As[buf][(wm + i * 16 + li) * BK + lg * 8]);
        #pragma unroll
        for (int i = 0; i < 4; ++i)
            bfr[i] = *reinterpret_cast<const bf16x8*>(&Bs[buf][(wn + i * 16 + li) * BK + lg * 8]);
        #pragma unroll
        for (int mi = 0; mi < MI; ++mi)
            #pragma unroll
            for (int ni = 0; ni < 4; ++ni)
                acc[mi][ni] = __builtin_amdgcn_mfma_f32_16x16x32_bf16(af[mi], bfr[ni], acc[mi][ni], 0, 0, 0);
        __syncthreads();
        buf ^= 1;
    }

    // epilogue; C/D layout: col = lane&15, row = (lane>>4)*4 + reg
    #pragma unroll
    for (int mi = 0; mi < MI; ++mi) {
        #pragma unroll
        for (int r = 0; r < 4; ++r) {
            int row = m0 + wm + mi * 16 + lg * 4 + r;
            if (EPI == EPI_GRAM) {
                float si = sq[row];
                float s = 0.f;
                #pragma unroll
                for (int ni = 0; ni < 4; ++ni) {
                    int col = n0 + wn + ni * 16 + li;
                    float d2 = si + sq[col] - 2.f * acc[mi][ni][r];
                    s += sqrtf(fmaxf(d2, 0.f));
                }
                s += __shfl_xor(s, 1); s += __shfl_xor(s, 2);
                s += __shfl_xor(s, 4); s += __shfl_xor(s, 8);
                if (li == 0) atomicAdd(&mean_acc[row], s);
            } else {
                #pragma unroll
                for (int ni = 0; ni < 4; ++ni) {
                    int col = n0 + wn + ni * 16 + li;
                    float v = acc[mi][ni][r] + bias[col];
                    if (EPI == EPI_BF16) outh[(size_t)row * N + col] = f2bf(v);
                    if (EPI == EPI_GELU) outh[(size_t)row * N + col] = f2bf(gelu_f(v));
                    if (EPI == EPI_RES) outf[(size_t)row * N + col] = res[(size_t)row * N + col] + v;
                    if (EPI == EPI_QKV) {
                        int which = col / 768;
                        int c2 = col - which * 768;
                        outh[(size_t)which * (8192 * 768) + (size_t)row * 768 + c2] = f2bf(v);
                    }
                }
            }
        }
    }
}

// ---------------- flash attention v3: QBLK=128, XCD swizzle ----------------
// grid (8, 12, 8); 4 waves; wave w owns q-rows [qt*128 + w*32, +32) as 2 frags
__launch_bounds__(256, 3)
__global__ void flash_attn(const ushort* __restrict__ q, const ushort* __restrict__ k,
                           const ushort* __restrict__ v, ushort* __restrict__ o) {
    // swizzle: 8 qt-blocks of one (h,b) land on one XCD -> K/V stay L2-hot
    int flat = blockIdx.x + 8 * (blockIdx.y + 12 * blockIdx.z);
    flat = (flat & 7) * 96 + (flat >> 3);
    int qt = flat & 7;
    int rem = flat >> 3;
    int h = rem % 12;
    int b = rem / 12;

    int t = threadIdx.x, w = t >> 6, l = t & 63;
    int lg = l >> 4, li = l & 15;

    __shared__ __align__(16) ushort Vt[2][64][72];  // V^T tile, stride 144B
    __shared__ __align__(16) ushort P[4][32][72];   // per-wave P[q][kv]

    const size_t hoff = (size_t)h * 64;
    const size_t bbase = (size_t)b * 1024 * 768;

    bf16x8 qf[2][2];
    #pragma unroll
    for (int f = 0; f < 2; ++f) {
        int qrow = qt * 128 + w * 32 + f * 16 + li;
        const ushort* qp = &q[bbase + (size_t)qrow * 768 + hoff];
        qf[f][0] = *reinterpret_cast<const bf16x8*>(qp + lg * 8);
        qf[f][1] = *reinterpret_cast<const bf16x8*>(qp + 32 + lg * 8);
    }

    float m_[2][4], ell[2][4];
    f32x4 oacc[2][4];
    #pragma unroll
    for (int f = 0; f < 2; ++f)
        #pragma unroll
        for (int r = 0; r < 4; ++r) { m_[f][r] = -1e30f; ell[f][r] = 0.f; }
    #pragma unroll
    for (int f = 0; f < 2; ++f)
        #pragma unroll
        for (int n = 0; n < 4; ++n) oacc[f][n] = f32x4{0.f, 0.f, 0.f, 0.f};

    // V staging: lane owns kv-row (t&63), d-chunks vc and vc+4 (column writes)
    int vrow = t & 63;
    int vc = t >> 6;
    const ushort* vbase = &v[bbase + hoff];

    ushort8 vv0 = *reinterpret_cast<const ushort8*>(&vbase[(size_t)vrow * 768 + vc * 8]);
    ushort8 vv1 = *reinterpret_cast<const ushort8*>(&vbase[(size_t)vrow * 768 + (vc + 4) * 8]);

    for (int jt = 0; jt < 16; ++jt) {
        int j0 = jt * 64, buf = jt & 1;
        #pragma unroll
        for (int i = 0; i < 8; ++i) Vt[buf][vc * 8 + i][vrow] = vv0[i];
        #pragma unroll
        for (int i = 0; i < 8; ++i) Vt[buf][(vc + 4) * 8 + i][vrow] = vv1[i];
        if (jt < 15) {
            vv0 = *reinterpret_cast<const ushort8*>(&vbase[(size_t)(j0 + 64 + vrow) * 768 + vc * 8]);
            vv1 = *reinterpret_cast<const ushort8*>(&vbase[(size_t)(j0 + 64 + vrow) * 768 + (vc + 4) * 8]);
        }
        // K loads (L2-hot after swizzle), shared by both q-frags
        bf16x8 kf0[4], kf1[4];
        #pragma unroll
        for (int jj = 0; jj < 4; ++jj) {
            const ushort* kp = &k[bbase + (size_t)(j0 + jj * 16 + li) * 768 + hoff];
            kf0[jj] = *reinterpret_cast<const bf16x8*>(kp + lg * 8);
            kf1[jj] = *reinterpret_cast<const bf16x8*>(kp + 32 + lg * 8);
        }
        f32x4 s[2][4];
        #pragma unroll
        for (int jj = 0; jj < 4; ++jj)
            #pragma unroll
            for (int f = 0; f < 2; ++f) {
                f32x4 a = {0.f, 0.f, 0.f, 0.f};
                a = __builtin_amdgcn_mfma_f32_16x16x32_bf16(qf[f][0], kf0[jj], a, 0, 0, 0);
                a = __builtin_amdgcn_mfma_f32_16x16x32_bf16(qf[f][1], kf1[jj], a, 0, 0, 0);
                s[f][jj] = a * 0.125f;
            }
        // online softmax per frag; lane holds S[q=lg*4+r][kv=jj*16+li]
        #pragma unroll
        for (int f = 0; f < 2; ++f) {
            float mt[4];
            #pragma unroll
            for (int r = 0; r < 4; ++r)
                mt[r] = fmaxf(fmaxf(s[f][0][r], s[f][1][r]), fmaxf(s[f][2][r], s[f][3][r]));
            #pragma unroll
            for (int r = 0; r < 4; ++r) {
                mt[r] = fmaxf(mt[r], __shfl_xor(mt[r], 1));
                mt[r] = fmaxf(mt[r], __shfl_xor(mt[r], 2));
                mt[r] = fmaxf(mt[r], __shfl_xor(mt[r], 4));
                mt[r] = fmaxf(mt[r], __shfl_xor(mt[r], 8));
            }
            float al[4], ps[4];
            #pragma unroll
            for (int r = 0; r < 4; ++r) {
                float mn = fmaxf(m_[f][r], mt[r]);
                al[r] = __expf(m_[f][r] - mn);
                m_[f][r] = mn;
                float p0 = __expf(s[f][0][r] - mn);
                float p1 = __expf(s[f][1][r] - mn);
                float p2 = __expf(s[f][2][r] - mn);
                float p3 = __expf(s[f][3][r] - mn);
                s[f][0][r] = p0; s[f][1][r] = p1; s[f][2][r] = p2; s[f][3][r] = p3;
                ps[r] = (p0 + p1) + (p2 + p3);
            }
            #pragma unroll
            for (int r = 0; r < 4; ++r) {
                ps[r] += __shfl_xor(ps[r], 1); ps[r] += __shfl_xor(ps[r], 2);
                ps[r] += __shfl_xor(ps[r], 4); ps[r] += __shfl_xor(ps[r], 8);
                ell[f][r] = ell[f][r] * al[r] + ps[r];
            }
            #pragma unroll
            for (int n = 0; n < 4; ++n)
                #pragma unroll
                for (int r = 0; r < 4; ++r) oacc[f][n][r] *= al[r];
            #pragma unroll
            for (int jj = 0; jj < 4; ++jj)
                #pragma unroll
                for (int r = 0; r < 4; ++r)
                    P[w][f * 16 + lg * 4 + r][jj * 16 + li] = f2bf(s[f][jj][r]);
        }
        __syncthreads();  // Vt[buf] staged by all waves
        // PV: O[f] += P[f][16x64] @ V[64x64]
        bf16x8 pf[2][2];
        #pragma unroll
        for (int f = 0; f < 2; ++f) {
            pf[f][0] = *reinterpret_cast<const bf16x8*>(&P[w][f * 16 + li][lg * 8]);
            pf[f][1] = *reinterpret_cast<const bf16x8*>(&P[w][f * 16 + li][32 + lg * 8]);
        }
        #pragma unroll
        for (int n = 0; n < 4; ++n) {
            bf16x8 vf0 = *reinterpret_cast<const bf16x8*>(&Vt[buf][n * 16 + li][lg * 8]);
            bf16x8 vf1 = *reinterpret_cast<const bf16x8*>(&Vt[buf][n * 16 + li][32 + lg * 8]);
            #pragma unroll
            for (int f = 0; f < 2; ++f) {
                oacc[f][n] = __builtin_amdgcn_mfma_f32_16x16x32_bf16(pf[f][0], vf0, oacc[f][n], 0, 0, 0);
                oacc[f][n] = __builtin_amdgcn_mfma_f32_16x16x32_bf16(pf[f][1], vf1, oacc[f][n], 0, 0, 0);
            }
        }
    }
    #pragma unroll
    for (int f = 0; f < 2; ++f)
        #pragma unroll
        for (int n = 0; n < 4; ++n)
            #pragma unroll
            for (int r = 0; r < 4; ++r) {
                int row = qt * 128 + w * 32 + f * 16 + lg * 4 + r;
                o[bbase + (size_t)row * 768 + hoff + n * 16 + li] = f2bf(oacc[f][n][r] / ell[f][r]);
            }
}

// ---------------------------------------------------------------------------
extern "C" void kernel_launch(void* const* d_in, const int* in_sizes, int n_in,
                              void* d_out, int out_size, void* d_ws, size_t ws_size,
                              hipStream_t stream) {
    const float* x = (const float*)d_in[0];
    const float* dp_w = (const float*)d_in[1];
    const float* dp_b = (const float*)d_in[2];
    const float* se_w1 = (const float*)d_in[3];
    const float* se_b1 = (const float*)d_in[4];
    const float* se_w2 = (const float*)d_in[5];
    const float* se_b2 = (const float*)d_in[6];
    const float* wq = (const float*)d_in[7];  const float* bq = (const float*)d_in[8];
    const float* wk = (const float*)d_in[9];  const float* bk = (const float*)d_in[10];
    const float* wv = (const float*)d_in[11]; const float* bv = (const float*)d_in[12];
    const float* wo = (const float*)d_in[13]; const float* bo = (const float*)d_in[14];
    const float* gw1 = (const float*)d_in[15]; const float* gb1 = (const float*)d_in[16];
    const float* gw2 = (const float*)d_in[17]; const float* gb2 = (const float*)d_in[18];
    const float* n1g = (const float*)d_in[19]; const float* n1b = (const float*)d_in[20];
    const float* n2g = (const float*)d_in[21]; const float* n2b = (const float*)d_in[22];
    float* out = (float*)d_out;

    constexpr size_t SZ_ACT = (size_t)8192 * 768 * 2;  // bytes per bf16 activation
    char* W = (char*)d_ws;
    ushort* xb = (ushort*)(W);                  // bf16 x; later reused as xn
    ushort* q_ = (ushort*)(W + SZ_ACT);
    ushort* k_ = (ushort*)(W + 2 * SZ_ACT);
    ushort* v_ = (ushort*)(W + 3 * SZ_ACT);
    ushort* o_ = (ushort*)(W + 4 * SZ_ACT);
    ushort* hsp = q_;                           // spatial h (before q is live)
    ushort* hff = q_;                           // FFN hidden (50 MB spans q..o)
    ushort* wqt = (ushort*)(W + 5 * SZ_ACT);    // contiguous qkv weight [2304][768]
    ushort* wkt = wqt + (size_t)768 * 768;
    ushort* wvt = wkt + (size_t)768 * 768;
    ushort* wot = wvt + (size_t)768 * 768;
    ushort* sw2t = wot + (size_t)768 * 768;
    ushort* g1t = sw2t + (size_t)768 * 768;
    ushort* g2t = g1t + (size_t)768 * 3072;
    float* sqv = (float*)(g2t + (size_t)3072 * 768);
    float* meanv = sqv + 8192;
    float* Avec = meanv + 8192;
    float* Cvec = Avec + 768;
    float* bqkv = Cvec + 768;                   // concat bias [2304]

    dim3 tb(32, 8);
    transpose_to_bf16<<<dim3(24, 24), tb, 0, stream>>>(se_w2, sw2t, 768, 768);
    transpose_to_bf16<<<dim3(24, 24), tb, 0, stream>>>(wq, wqt, 768, 768);
    transpose_to_bf16<<<dim3(24, 24), tb, 0, stream>>>(wk, wkt, 768, 768);
    transpose_to_bf16<<<dim3(24, 24), tb, 0, stream>>>(wv, wvt, 768, 768);
    transpose_to_bf16<<<dim3(24, 24), tb, 0, stream>>>(wo, wot, 768, 768);
    transpose_to_bf16<<<dim3(24, 96), tb, 0, stream>>>(gw1, g1t, 768, 3072);
    transpose_to_bf16<<<dim3(96, 24), tb, 0, stream>>>(gw2, g2t, 3072, 768);
    hipMemcpyAsync(bqkv, bq, 768 * sizeof(float), hipMemcpyDeviceToDevice, stream);
    hipMemcpyAsync(bqkv + 768, bk, 768 * sizeof(float), hipMemcpyDeviceToDevice, stream);
    hipMemcpyAsync(bqkv + 1536, bv, 768 * sizeof(float), hipMemcpyDeviceToDevice, stream);

    rowstat<<<8192, 256, 0, stream>>>(x, xb, sqv);
    precomp_ac<<<3, 256, 0, stream>>>(dp_w, dp_b, se_w1, se_b1, Avec, Cvec);
    hipMemsetAsync(meanv, 0, 8192 * sizeof(float), stream);

    // Gram -> distance row-sums (one batch per XCD after swizzle)
    gemm_bt<EPI_GRAM, 128><<<dim3(8, 8, 8), 256, 0, stream>>>(xb, xb, 1024, 1024, 768,
                                                              nullptr, nullptr, nullptr, nullptr, sqv, meanv);
    hgen<<<8192, 256, 0, stream>>>(meanv, Avec, Cvec, hsp);
    // x = x + h @ se_w2 + se_b2  -> d_out (fp32 residual stream)
    gemm_bt<EPI_RES, 64><<<dim3(64, 12), 256, 0, stream>>>(hsp, sw2t, 8192, 768, 768,
                                                           se_b2, x, out, nullptr, nullptr, nullptr);
    // attention block
    lnorm<<<8192, 256, 0, stream>>>(out, n1g, n1b, xb);
    gemm_bt<EPI_QKV, 128><<<dim3(64, 18), 256, 0, stream>>>(xb, wqt, 8192, 2304, 768,
                                                            bqkv, nullptr, nullptr, q_, nullptr, nullptr);
    flash_attn<<<dim3(8, 12, 8), 256, 0, stream>>>(q_, k_, v_, o_);
    gemm_bt<EPI_RES, 64><<<dim3(64, 12), 256, 0, stream>>>(o_, wot, 8192, 768, 768,
                                                           bo, out, out, nullptr, nullptr, nullptr);
    // FFN block
    lnorm<<<8192, 256, 0, stream>>>(out, n2g, n2b, xb);
    gemm_bt<EPI_GELU, 128><<<dim3(64, 24), 256, 0, stream>>>(xb, g1t, 8192, 3072, 768,
                                                             gb1, nullptr, nullptr, hff, nullptr, nullptr);
    gemm_bt<EPI_RES, 64><<<dim3(64, 12), 256, 0, stream>>>(hff, g2t, 8192, 768, 3072,
                                                           gb2, out, out, nullptr, nullptr, nullptr);
}